// Round 3
// baseline (196.858 us; speedup 1.0000x reference)
//
#include <hip/hip_runtime.h>

// BCH truncated series on 3D periodic velocity fields — x-marching version 2.
// out_i = L_i + R_i + 0.25 * sum_j [ dL_i^j * R_j - dR_i^j * L_j ]
// (central differences, circulant bounds, channels-first (B,D,X,Y,Z)).
//
// v2 changes vs v1:
//  - XSEG 8 -> 4: grid 512 -> 1024 blocks = 4 blocks/CU = 4 waves/SIMD
//    (v1 was grid-limited to 2 waves/SIMD, occupancy 17%).
//  - y-halo rows staged through LDS ((YT+2)-row tile) instead of being held
//    in registers across the barrier: kills 48 live VGPRs + cndmask selects.
//  - __launch_bounds__(256,4) to pin VGPR <= 128 (waves/SIMD halve past 128).
//  - nontemporal float4 output stores (write-once data; keep L2/L3 for input).

namespace {
constexpr int Xd = 128, Yd = 128, Zd = 128, Dd = 3;
constexpr int Sd  = Xd * Yd * Zd;   // channel stride
constexpr int YZd = Yd * Zd;        // x-plane stride
constexpr int XSEG = 4;             // x-planes marched per block
constexpr int YT   = 8;             // y rows per block
constexpr int ZC   = 32;            // float4 chunks per z-line

typedef float f32x4_t __attribute__((ext_vector_type(4)));

__device__ inline float4 f4sub(float4 a, float4 b) {
    return make_float4(a.x - b.x, a.y - b.y, a.z - b.z, a.w - b.w);
}
__device__ inline float4 f4add(float4 a, float4 b) {
    return make_float4(a.x + b.x, a.y + b.y, a.z + b.z, a.w + b.w);
}
__device__ inline float4 f4mul(float4 a, float4 b) {
    return make_float4(a.x * b.x, a.y * b.y, a.z * b.z, a.w * b.w);
}
__device__ inline float4 f4fma(float4 a, float4 b, float4 c) {
    return make_float4(fmaf(a.x, b.x, c.x), fmaf(a.y, b.y, c.y),
                       fmaf(a.z, b.z, c.z), fmaf(a.w, b.w, c.w));
}
// c - a*b
__device__ inline float4 f4fms(float4 a, float4 b, float4 c) {
    return make_float4(fmaf(-a.x, b.x, c.x), fmaf(-a.y, b.y, c.y),
                       fmaf(-a.z, b.z, c.z), fmaf(-a.w, b.w, c.w));
}
__device__ inline void store_nt(float* p, float4 v) {
    __builtin_nontemporal_store(*(const f32x4_t*)&v, (f32x4_t*)p);
}
} // namespace

__global__ void __launch_bounds__(256, 4)
bch_march(const float* __restrict__ L, const float* __restrict__ R,
          float* __restrict__ O)
{
    // [0..2]=L channels, [3..5]=R channels; rows 1..YT = center, 0 / YT+1 = halo
    __shared__ float4 sP[2 * Dd][YT + 2][ZC];   // 30 KB

    const int t  = threadIdx.x;
    const int zc = t & 31;          // z chunk (float4) within line
    const int ly = t >> 5;          // local y row 0..7

    int bb = blockIdx.x;            // grid = 2 * 16 * 32 = 1024
    const int xs = bb & 31; bb >>= 5;   // x segment
    const int yt = bb & 15; bb >>= 4;   // y tile
    const int b  = bb;

    const int y  = yt * YT + ly;
    const int z0 = zc * 4;
    const int x0 = xs * XSEG;

    const int fbase = b * (Dd * Sd) + y * Zd + z0;
    const float* pL = L + fbase;
    const float* pR = R + fbase;
    float*       pO = O + fbase;

    const int oym = (((y - 1) & 127) - y) * Zd;   // wrapped y-1 row offset
    const int oyp = (((y + 1) & 127) - y) * Zd;   // wrapped y+1 row offset
    const int zlm = (zc + 31) & 31;   // shfl source lane for z-1 (.w)
    const int zlp = (zc + 1) & 31;    // shfl source lane for z+4 (.x)

    float4 AL[3], AR[3], BL[3], BR[3], CL[3], CR[3], DL[3], DR[3];

    auto loadP = [&](float4 (&PL)[3], float4 (&PR)[3], int xp) {
        const int off = xp * YZd;
#pragma unroll
        for (int d = 0; d < 3; ++d) {
            PL[d] = *(const float4*)(pL + off + d * Sd);
            PR[d] = *(const float4*)(pR + off + d * Sd);
        }
    };

    loadP(AL, AR, (x0 + 127) & 127);   // x0 - 1 (wrapped)
    loadP(BL, BR, x0);
    loadP(CL, CR, (x0 + 1) & 127);

    const bool lo = (ly == 0);
    const bool hi = (ly == YT - 1);
    const int  oyh = lo ? oym : oyp;          // halo row offset for edge threads
    const int  hrow = lo ? 0 : YT + 1;        // LDS halo row index

#pragma unroll
    for (int s = 0; s < XSEG; ++s) {
        const int xoff = (x0 + s) * YZd;

        // Prefetch plane x+2 (becomes C after rotation) — a full iteration
        // of latency tolerance for the center loads.
        if (s < XSEG - 1) loadP(DL, DR, (x0 + s + 2) & 127);

        // Halo rows (y-1 for ly==0, y+8 for ly==7) -> registers -> LDS.
        float4 H[6];
        if (lo | hi) {
#pragma unroll
            for (int d = 0; d < 3; ++d) {
                H[d]     = *(const float4*)(pL + xoff + oyh + d * Sd);
                H[3 + d] = *(const float4*)(pR + xoff + oyh + d * Sd);
            }
        }

        // Stage current plane centers (+ halo) in LDS.
#pragma unroll
        for (int d = 0; d < 3; ++d) {
            sP[d][ly + 1][zc]     = BL[d];
            sP[3 + d][ly + 1][zc] = BR[d];
        }
        if (lo | hi) {
#pragma unroll
            for (int d = 0; d < 6; ++d) sP[d][hrow][zc] = H[d];
        }
        __syncthreads();

        // y-neighbors: uniform LDS reads (halo rows included in tile).
        float4 yLm[3], yRm[3], yLp[3], yRp[3];
#pragma unroll
        for (int d = 0; d < 3; ++d) {
            yLm[d] = sP[d][ly][zc];
            yLp[d] = sP[d][ly + 2][zc];
            yRm[d] = sP[3 + d][ly][zc];
            yRp[d] = sP[3 + d][ly + 2][zc];
        }

#pragma unroll
        for (int i = 0; i < 3; ++i) {
            // j = 0 (x): from register window
            float4 dl = f4sub(CL[i], AL[i]);
            float4 dr = f4sub(CR[i], AR[i]);
            float4 br = f4fms(dr, BL[0], f4mul(dl, BR[0]));

            // j = 1 (y): from LDS
            dl = f4sub(yLp[i], yLm[i]);
            dr = f4sub(yRp[i], yRm[i]);
            br = f4fms(dr, BL[1], f4fma(dl, BR[1], br));

            // j = 2 (z): shift-in-register + width-32 shuffles (wrap in line)
            const float lzm = __shfl(BL[i].w, zlm, 32);
            const float lzp = __shfl(BL[i].x, zlp, 32);
            const float rzm = __shfl(BR[i].w, zlm, 32);
            const float rzp = __shfl(BR[i].x, zlp, 32);
            dl = make_float4(BL[i].y - lzm, BL[i].z - BL[i].x,
                             BL[i].w - BL[i].y, lzp - BL[i].z);
            dr = make_float4(BR[i].y - rzm, BR[i].z - BR[i].x,
                             BR[i].w - BR[i].y, rzp - BR[i].z);
            br = f4fms(dr, BL[2], f4fma(dl, BR[2], br));

            float4 out = f4add(BL[i], BR[i]);
            const float4 q = make_float4(0.25f, 0.25f, 0.25f, 0.25f);
            out = f4fma(q, br, out);
            store_nt(pO + xoff + i * Sd, out);
        }
        __syncthreads();   // protect LDS before next iteration's writes

        if (s < XSEG - 1) {
#pragma unroll
            for (int d = 0; d < 3; ++d) {
                AL[d] = BL[d]; BL[d] = CL[d]; CL[d] = DL[d];
                AR[d] = BR[d]; BR[d] = CR[d]; CR[d] = DR[d];
            }
        }
    }
}

extern "C" void kernel_launch(void* const* d_in, const int* in_sizes, int n_in,
                              void* d_out, int out_size, void* d_ws, size_t ws_size,
                              hipStream_t stream)
{
    const float* L = (const float*)d_in[0];
    const float* R = (const float*)d_in[1];
    float*       O = (float*)d_out;

    const int nblocks = 2 * (Yd / YT) * (Xd / XSEG);   // 1024
    bch_march<<<dim3(nblocks), dim3(256), 0, stream>>>(L, R, O);
}

// Round 4
// 146.730 us; speedup vs baseline: 1.3416x; 1.3416x over previous
//
#include <hip/hip_runtime.h>

// BCH truncated series on 3D periodic velocity fields — x-marching version 3.
// out_i = L_i + R_i + 0.25 * sum_j [ dL_i^j * R_j - dR_i^j * L_j ]
// (central differences, circulant bounds, channels-first (B,D,X,Y,Z)).
//
// v3 = v1 (measured 50.6 us/dispatch, VGPR=128, no spill) with EXACTLY ONE
// change: XSEG 8 -> 4, doubling the grid to 1024 blocks = 4 blocks/CU
// (v1 was grid-limited: 512 blocks -> 2 blocks/CU, occupancy 17%).
// NOTE: keep __launch_bounds__(256, 2). (256, 4) made the allocator squeeze
// to 64 VGPRs and spill the plane window to scratch: +110 MB HBM writes,
// dur 50 -> 103 us (measured R3... er, R2 bench). Do not re-pin.

namespace {
constexpr int Xd = 128, Yd = 128, Zd = 128, Dd = 3;
constexpr int Sd  = Xd * Yd * Zd;   // channel stride
constexpr int YZd = Yd * Zd;        // x-plane stride
constexpr int XSEG = 4;             // x-planes marched per block
constexpr int YT   = 8;             // y rows per block
constexpr int ZC   = 32;            // float4 chunks per z-line

__device__ inline float4 f4sub(float4 a, float4 b) {
    return make_float4(a.x - b.x, a.y - b.y, a.z - b.z, a.w - b.w);
}
__device__ inline float4 f4add(float4 a, float4 b) {
    return make_float4(a.x + b.x, a.y + b.y, a.z + b.z, a.w + b.w);
}
__device__ inline float4 f4mul(float4 a, float4 b) {
    return make_float4(a.x * b.x, a.y * b.y, a.z * b.z, a.w * b.w);
}
__device__ inline float4 f4fma(float4 a, float4 b, float4 c) {
    return make_float4(fmaf(a.x, b.x, c.x), fmaf(a.y, b.y, c.y),
                       fmaf(a.z, b.z, c.z), fmaf(a.w, b.w, c.w));
}
// c - a*b
__device__ inline float4 f4fms(float4 a, float4 b, float4 c) {
    return make_float4(fmaf(-a.x, b.x, c.x), fmaf(-a.y, b.y, c.y),
                       fmaf(-a.z, b.z, c.z), fmaf(-a.w, b.w, c.w));
}
} // namespace

__global__ void __launch_bounds__(256, 2)
bch_march(const float* __restrict__ L, const float* __restrict__ R,
          float* __restrict__ O)
{
    __shared__ float4 sP[2 * Dd][YT][ZC];   // 24 KB: [0..2]=L ch, [3..5]=R ch

    const int t  = threadIdx.x;
    const int zc = t & 31;          // z chunk (float4) within line
    const int ly = t >> 5;          // local y row 0..7

    int bb = blockIdx.x;            // grid = 2 * 16 * 32 = 1024
    const int xs = bb & 31; bb >>= 5;   // x segment
    const int yt = bb & 15; bb >>= 4;   // y tile
    const int b  = bb;

    const int y  = yt * YT + ly;
    const int z0 = zc * 4;
    const int x0 = xs * XSEG;

    const int fbase = b * (Dd * Sd) + y * Zd + z0;
    const float* pL = L + fbase;
    const float* pR = R + fbase;
    float*       pO = O + fbase;

    const int oym = (((y - 1) & 127) - y) * Zd;   // wrapped y-1 row offset
    const int oyp = (((y + 1) & 127) - y) * Zd;   // wrapped y+1 row offset
    const int zlm = (zc + 31) & 31;   // shfl source lane for z-1 (.w)
    const int zlp = (zc + 1) & 31;    // shfl source lane for z+4 (.x)

    float4 AL[3], AR[3], BL[3], BR[3], CL[3], CR[3], DL[3], DR[3];

    auto loadP = [&](float4 (&PL)[3], float4 (&PR)[3], int xp) {
        const int off = xp * YZd;
#pragma unroll
        for (int d = 0; d < 3; ++d) {
            PL[d] = *(const float4*)(pL + off + d * Sd);
            PR[d] = *(const float4*)(pR + off + d * Sd);
        }
    };

    loadP(AL, AR, (x0 + 127) & 127);   // x0 - 1 (wrapped)
    loadP(BL, BR, x0);
    loadP(CL, CR, (x0 + 1) & 127);

#pragma unroll
    for (int s = 0; s < XSEG; ++s) {
        const int x    = x0 + s;
        const int xoff = x * YZd;

        // Prefetch plane x+2 (becomes C after rotation) — a full iteration
        // of latency tolerance for the center loads.
        if (s < XSEG - 1) loadP(DL, DR, (x + 2) & 127);

        // Halo rows from global for tile-boundary threads.
        float4 HmL[3], HmR[3], HpL[3], HpR[3];
        if (ly == 0) {
#pragma unroll
            for (int d = 0; d < 3; ++d) {
                HmL[d] = *(const float4*)(pL + xoff + oym + d * Sd);
                HmR[d] = *(const float4*)(pR + xoff + oym + d * Sd);
            }
        }
        if (ly == YT - 1) {
#pragma unroll
            for (int d = 0; d < 3; ++d) {
                HpL[d] = *(const float4*)(pL + xoff + oyp + d * Sd);
                HpR[d] = *(const float4*)(pR + xoff + oyp + d * Sd);
            }
        }

        // Stage current plane centers in LDS.
#pragma unroll
        for (int d = 0; d < 3; ++d) {
            sP[d][ly][zc]     = BL[d];
            sP[3 + d][ly][zc] = BR[d];
        }
        __syncthreads();

        // y-neighbors: LDS for interior rows, global halo at tile edges.
        const int lym = (ly == 0) ? 0 : ly - 1;          // clamped (safe read)
        const int lyp = (ly == YT - 1) ? YT - 1 : ly + 1;
        float4 yLm[3], yRm[3], yLp[3], yRp[3];
#pragma unroll
        for (int d = 0; d < 3; ++d) {
            yLm[d] = sP[d][lym][zc];     if (ly == 0)      yLm[d] = HmL[d];
            yRm[d] = sP[3 + d][lym][zc]; if (ly == 0)      yRm[d] = HmR[d];
            yLp[d] = sP[d][lyp][zc];     if (ly == YT - 1) yLp[d] = HpL[d];
            yRp[d] = sP[3 + d][lyp][zc]; if (ly == YT - 1) yRp[d] = HpR[d];
        }

#pragma unroll
        for (int i = 0; i < 3; ++i) {
            // j = 0 (x): from register window
            float4 dl = f4sub(CL[i], AL[i]);
            float4 dr = f4sub(CR[i], AR[i]);
            float4 br = f4fms(dr, BL[0], f4mul(dl, BR[0]));

            // j = 1 (y): from LDS / halo
            dl = f4sub(yLp[i], yLm[i]);
            dr = f4sub(yRp[i], yRm[i]);
            br = f4fms(dr, BL[1], f4fma(dl, BR[1], br));

            // j = 2 (z): shift-in-register + width-32 shuffles (wrap in line)
            const float lzm = __shfl(BL[i].w, zlm, 32);
            const float lzp = __shfl(BL[i].x, zlp, 32);
            const float rzm = __shfl(BR[i].w, zlm, 32);
            const float rzp = __shfl(BR[i].x, zlp, 32);
            dl = make_float4(BL[i].y - lzm, BL[i].z - BL[i].x,
                             BL[i].w - BL[i].y, lzp - BL[i].z);
            dr = make_float4(BR[i].y - rzm, BR[i].z - BR[i].x,
                             BR[i].w - BR[i].y, rzp - BR[i].z);
            br = f4fms(dr, BL[2], f4fma(dl, BR[2], br));

            float4 out = f4add(BL[i], BR[i]);
            const float4 q = make_float4(0.25f, 0.25f, 0.25f, 0.25f);
            out = f4fma(q, br, out);
            *(float4*)(pO + xoff + i * Sd) = out;
        }
        __syncthreads();   // protect LDS before next iteration's writes

        if (s < XSEG - 1) {
#pragma unroll
            for (int d = 0; d < 3; ++d) {
                AL[d] = BL[d]; BL[d] = CL[d]; CL[d] = DL[d];
                AR[d] = BR[d]; BR[d] = CR[d]; CR[d] = DR[d];
            }
        }
    }
}

extern "C" void kernel_launch(void* const* d_in, const int* in_sizes, int n_in,
                              void* d_out, int out_size, void* d_ws, size_t ws_size,
                              hipStream_t stream)
{
    const float* L = (const float*)d_in[0];
    const float* R = (const float*)d_in[1];
    float*       O = (float*)d_out;

    const int nblocks = 2 * (Yd / YT) * (Xd / XSEG);   // 1024
    bch_march<<<dim3(nblocks), dim3(256), 0, stream>>>(L, R, O);
}

// Round 5
// 137.479 us; speedup vs baseline: 1.4319x; 1.0673x over previous
//
#include <hip/hip_runtime.h>

// BCH truncated series on 3D periodic velocity fields — v4: plane-gather hybrid.
// out_i = L_i + R_i + 0.25 * sum_j [ dL_i^j * R_j - dR_i^j * L_j ]
// (central differences, circulant bounds, channels-first (B,D,X,Y,Z)).
//
// v4 rationale (Little's law: throughput = waves/CU x in-flight-loads/wave):
//  - NO x-marching window (v1/v3's 24 live float4 pinned VGPR=128 -> 2 blocks/CU,
//    occupancy stuck at 17% regardless of grid size).
//  - One x-plane per block; x+-1 planes GATHERED (12 independent float4 loads,
//    L2/L3 hits) issued up front; all ~19 loads ride one barrier drain = one
//    latency window instead of 4-5 register-starved batches (v0's failure mode).
//  - y+-1 from LDS-staged center plane, halo rows in LDS (v2-verified scheme).
//  - z+-1 via width-32 shuffles.
//  - grid = 4096 blocks -> 16 blocks/CU of work; occupancy now VGPR-limited only.
//  - NO __launch_bounds__ min-waves pin (R2: (256,4) squeezed to 64 VGPR and
//    spilled +110 MB to scratch, dur 50 -> 103 us).

namespace {
constexpr int Xd = 128, Yd = 128, Zd = 128, Dd = 3;
constexpr int Sd  = Xd * Yd * Zd;   // channel stride
constexpr int YZd = Yd * Zd;        // x-plane stride
constexpr int YT  = 8;              // y rows per block
constexpr int ZC  = 32;             // float4 chunks per z-line

__device__ inline float4 f4sub(float4 a, float4 b) {
    return make_float4(a.x - b.x, a.y - b.y, a.z - b.z, a.w - b.w);
}
__device__ inline float4 f4add(float4 a, float4 b) {
    return make_float4(a.x + b.x, a.y + b.y, a.z + b.z, a.w + b.w);
}
__device__ inline float4 f4mul(float4 a, float4 b) {
    return make_float4(a.x * b.x, a.y * b.y, a.z * b.z, a.w * b.w);
}
__device__ inline float4 f4fma(float4 a, float4 b, float4 c) {
    return make_float4(fmaf(a.x, b.x, c.x), fmaf(a.y, b.y, c.y),
                       fmaf(a.z, b.z, c.z), fmaf(a.w, b.w, c.w));
}
// c - a*b
__device__ inline float4 f4fms(float4 a, float4 b, float4 c) {
    return make_float4(fmaf(-a.x, b.x, c.x), fmaf(-a.y, b.y, c.y),
                       fmaf(-a.z, b.z, c.z), fmaf(-a.w, b.w, c.w));
}
} // namespace

__global__ void __launch_bounds__(256)
bch_plane(const float* __restrict__ L, const float* __restrict__ R,
          float* __restrict__ O)
{
    // [0..2]=L channels, [3..5]=R channels; rows 1..YT = center, 0 / YT+1 = halo
    __shared__ float4 sP[2 * Dd][YT + 2][ZC];   // 30 KB

    const int t  = threadIdx.x;
    const int zc = t & 31;          // z chunk (float4) within line
    const int ly = t >> 5;          // local y row 0..7

    int bb = blockIdx.x;            // grid = 16 * 128 * 2 = 4096
    const int yt = bb & 15; bb >>= 4;    // y tile (low bits: 16 consecutive
    const int x  = bb & 127; bb >>= 7;   //   blocks share one x-neighborhood)
    const int b  = bb;

    const int y  = yt * YT + ly;
    const int z0 = zc * 4;

    const int fbase = b * (Dd * Sd) + x * YZd + y * Zd + z0;
    const float* pL = L + fbase;
    const float* pR = R + fbase;
    float*       pO = O + fbase;

    const int oxp = (((x + 1) & 127) - x) * YZd;  // wrapped x+1 plane offset
    const int oxm = (((x - 1) & 127) - x) * YZd;  // wrapped x-1 plane offset
    const int oym = (((y - 1) & 127) - y) * Zd;   // wrapped y-1 row offset
    const int oyp = (((y + 1) & 127) - y) * Zd;   // wrapped y+1 row offset
    const int zlm = (zc + 31) & 31;   // shfl source lane for z-1 (.w)
    const int zlp = (zc + 1) & 31;    // shfl source lane for z+4 (.x)

    // ---- issue ALL global loads up front (one latency window) ----
    float4 BL[3], BR[3];              // center plane
    float4 XPL[3], XML[3], XPR[3], XMR[3];   // x+1 / x-1 gathers
#pragma unroll
    for (int d = 0; d < 3; ++d) {
        BL[d]  = *(const float4*)(pL + d * Sd);
        BR[d]  = *(const float4*)(pR + d * Sd);
        XPL[d] = *(const float4*)(pL + oxp + d * Sd);
        XML[d] = *(const float4*)(pL + oxm + d * Sd);
        XPR[d] = *(const float4*)(pR + oxp + d * Sd);
        XMR[d] = *(const float4*)(pR + oxm + d * Sd);
    }

    const bool lo = (ly == 0);
    const bool hi = (ly == YT - 1);
    if (lo | hi) {
        const int oyh  = lo ? oym : oyp;
        const int hrow = lo ? 0 : YT + 1;
        float4 H[6];
#pragma unroll
        for (int d = 0; d < 3; ++d) {
            H[d]     = *(const float4*)(pL + oyh + d * Sd);
            H[3 + d] = *(const float4*)(pR + oyh + d * Sd);
        }
#pragma unroll
        for (int d = 0; d < 6; ++d) sP[d][hrow][zc] = H[d];
    }

    // Stage center plane in LDS.
#pragma unroll
    for (int d = 0; d < 3; ++d) {
        sP[d][ly + 1][zc]     = BL[d];
        sP[3 + d][ly + 1][zc] = BR[d];
    }
    __syncthreads();

    // y-neighbors: uniform LDS reads (halo rows included in tile).
    float4 yLm[3], yRm[3], yLp[3], yRp[3];
#pragma unroll
    for (int d = 0; d < 3; ++d) {
        yLm[d] = sP[d][ly][zc];
        yLp[d] = sP[d][ly + 2][zc];
        yRm[d] = sP[3 + d][ly][zc];
        yRp[d] = sP[3 + d][ly + 2][zc];
    }

#pragma unroll
    for (int i = 0; i < 3; ++i) {
        // j = 0 (x): from gathered planes
        float4 dl = f4sub(XPL[i], XML[i]);
        float4 dr = f4sub(XPR[i], XMR[i]);
        float4 br = f4fms(dr, BL[0], f4mul(dl, BR[0]));

        // j = 1 (y): from LDS
        dl = f4sub(yLp[i], yLm[i]);
        dr = f4sub(yRp[i], yRm[i]);
        br = f4fms(dr, BL[1], f4fma(dl, BR[1], br));

        // j = 2 (z): shift-in-register + width-32 shuffles (wrap in line)
        const float lzm = __shfl(BL[i].w, zlm, 32);
        const float lzp = __shfl(BL[i].x, zlp, 32);
        const float rzm = __shfl(BR[i].w, zlm, 32);
        const float rzp = __shfl(BR[i].x, zlp, 32);
        dl = make_float4(BL[i].y - lzm, BL[i].z - BL[i].x,
                         BL[i].w - BL[i].y, lzp - BL[i].z);
        dr = make_float4(BR[i].y - rzm, BR[i].z - BR[i].x,
                         BR[i].w - BR[i].y, rzp - BR[i].z);
        br = f4fms(dr, BL[2], f4fma(dl, BR[2], br));

        float4 out = f4add(BL[i], BR[i]);
        const float4 q = make_float4(0.25f, 0.25f, 0.25f, 0.25f);
        out = f4fma(q, br, out);
        *(float4*)(pO + i * Sd) = out;
    }
}

extern "C" void kernel_launch(void* const* d_in, const int* in_sizes, int n_in,
                              void* d_out, int out_size, void* d_ws, size_t ws_size,
                              hipStream_t stream)
{
    const float* L = (const float*)d_in[0];
    const float* R = (const float*)d_in[1];
    float*       O = (float*)d_out;

    const int nblocks = (Yd / YT) * Xd * 2;   // 4096
    bch_plane<<<dim3(nblocks), dim3(256), 0, stream>>>(L, R, O);
}